// Round 5
// baseline (152.603 us; speedup 1.0000x reference)
//
#include <hip/hip_runtime.h>

// B=64, H=W=32, HW=1024, steps<=256, backtrack 255.
// Outputs: [histories 65536][paths 65536][pred_cost 65536] float32.
// Single fused kernel: 64 blocks (1 per batch) x 256 threads.
//   Phase 1 (all 256 thr): conv1(2->32)+ReLU, conv2(32->1)+sigmoid.
//            (unchanged, bit-identical accumulation order).
//   Phase 2 (wave 0 only): register-resident A* (round-2/4 structure) plus:
//     - par table in REGISTERS (par_r[16]): arm writes are lane-owned with
//       static reg indices {j0,j0+1} (same parity proof as g/vkey), so the
//       two per-step ds_writes disappear.
//     - REGISTER BACKTRACK: parents packed 10-bit into pp[6]; chase uses
//       uniform SALU index math + ternary word-select + v_lshrrev_b64 funnel
//       + readlane from owner, visited via per-lane path_m bitmask readlane.
//       ~70-90 cy/iter vs ~250-300 cy/iter of the old LDS pointer-chase
//       (two dependent ~120cy LDS reads per hop) -- the largest untouched
//       serial-latency block (~5-15us on the worst batch).
//     - single-readlane gsum: owner lane computes g[sel]+c[sel] locally
//       (bit-identical), one broadcast instead of two.
//     FREEZE BREAK: ballot==0 => fixed point => exact early exit.
//   Phase 3 (all): output writes (hist/path from per-lane bitmasks).

#define HW 1024

// DPP wave-64 u32 max step (compiler folds mov_dpp+max -> v_max_u32_dpp).
#define DPPMAX32(v, ctrl) do {                                                 \
    unsigned int _s = (unsigned int)__builtin_amdgcn_update_dpp(               \
        (int)(v), (int)(v), (ctrl), 0xf, 0xf, false);                          \
    (v) = (_s > (v)) ? _s : (v);                                               \
} while (0)

// Tournament-tree node repairs (value-only compare; tie keeps LEFT child =
// smaller index side; children cover contiguous index ranges => exact
// smallest-index tie-break).
#define PAIR_FIX(a_) { bool _r = vr[2*(a_)+1] > vr[2*(a_)];                    \
    pv[(a_)] = _r ? vr[2*(a_)+1] : vr[2*(a_)];                                 \
    pj[(a_)] = _r ? (unsigned)(2*(a_)+1) : (unsigned)(2*(a_)); }
#define QUAD_FIX(q_) { bool _r = pv[2*(q_)+1] > pv[2*(q_)];                    \
    qv[(q_)] = _r ? pv[2*(q_)+1] : pv[2*(q_)];                                 \
    qj[(q_)] = _r ? pj[2*(q_)+1] : pj[2*(q_)]; }
#define OCT_FIX(o_) { bool _r = qv[2*(o_)+1] > qv[2*(o_)];                     \
    ov[(o_)] = _r ? qv[2*(o_)+1] : qv[2*(o_)];                                 \
    oj[(o_)] = _r ? qj[2*(o_)+1] : qj[2*(o_)]; }
#define ROOT_FIX() { bool _r = ov[1] > ov[0];                                  \
    rv = _r ? ov[1] : ov[0]; rj = _r ? oj[1] : oj[0]; }

// One uniform arm of the A* update (J = j0, compile-time constant).
#define ASTAR_ARM(J) {                                                         \
    constexpr int JN = ((J) < 15) ? (J) + 1 : 15;                              \
    const float gj0 = gr[(J)], hj0v = hr[(J)], cj0 = cr[(J)];                  \
    const float gj1 = gr[JN],  hj1v = hr[JN],  cj1 = cr[JN];                   \
    /* owner lane computes g[sel]+c[sel] locally; one broadcast */             \
    float gcs = (jS_is_j0 ? gj0 : gj1) + (jS_is_j0 ? cj0 : cj1);               \
    const float gsum = __uint_as_float(                                        \
        (unsigned int)__builtin_amdgcn_readlane(                               \
            (int)__float_as_uint(gcs), owner));                                \
    const float gA = vjA_is_j0 ? gj0 : gj1;                                    \
    const float hA = vjA_is_j0 ? hj0v : hj1v;                                  \
    const float gB = jP_is_j0 ? gj0 : gj1;                                     \
    const float hB = jP_is_j0 ? hj0v : hj1v;                                   \
    idxA = canAn || (canAr && (gA > gsum));                                    \
    idxB = canBn || (canBr && (gB > gsum));                                    \
    float fA = 0.5f * (gsum + hA);                                             \
    unsigned int nvA = __float_as_uint(expf(__fmul_rn(-fA, C_INV)));           \
    float fB = 0.5f * (gsum + hB);                                             \
    unsigned int nvB = __float_as_uint(expf(__fmul_rn(-fB, C_INV)));           \
    const bool uA0 = idxA && vjA_is_j0, uB0 = idxB && jP_is_j0;                \
    const bool uA1 = idxA && !vjA_is_j0, uB1 = idxB && !jP_is_j0;              \
    const bool u0 = uA0 || uB0, u1 = uA1 || uB1;                               \
    if (u0) { gr[(J)] = gsum; vr[(J)] = uA0 ? nvA : nvB;                       \
              par_r[(J)] = (unsigned)sel; }                                    \
    if (u1) { gr[JN]  = gsum; vr[JN]  = uA1 ? nvA : nvB;                       \
              par_r[JN] = (unsigned)sel; }                                     \
    if (closeU &&  jS_is_j0) vr[(J)] = 0u;                                     \
    if (closeU && !jS_is_j0) vr[JN]  = 0u;                                     \
    constexpr int pa = (J) >> 1, pb = JN >> 1;                                 \
    PAIR_FIX(pa);                                                              \
    if constexpr (pb != pa) PAIR_FIX(pb);                                      \
    constexpr int qa = pa >> 1, qb = pb >> 1;                                  \
    QUAD_FIX(qa);                                                              \
    if constexpr (qb != qa) QUAD_FIX(qb);                                      \
    constexpr int oa = qa >> 1, ob = qb >> 1;                                  \
    OCT_FIX(oa);                                                               \
    if constexpr (ob != oa) OCT_FIX(ob);                                       \
    ROOT_FIX();                                                                \
  }

__global__ __launch_bounds__(256) void fused_nastar(
    const float* __restrict__ maps, const float* __restrict__ start,
    const float* __restrict__ goal, const float* __restrict__ w1,
    const float* __restrict__ b1, const float* __restrict__ w2,
    const float* __restrict__ b2, float* __restrict__ out_hist,
    float* __restrict__ out_path, float* __restrict__ out_cost) {
  __shared__ float hid[8][HW];            // 32 KB
  __shared__ float c_l[HW];               // 4 KB: cost (phase1 -> wave0 xfer)
  __shared__ unsigned int hist_lds[64];   // 256 B
  __shared__ unsigned int path_lds[64];   // 256 B

  const int t = threadIdx.x;
  const int b = blockIdx.x;
  const float C_INV = 0.17677669529663687f;  // float32(1/sqrt(32))

  const float* m_p = maps  + b * HW;
  const float* s_p = start + b * HW;
  const float* g_p = goal  + b * HW;

  // ---------------- Phase 1: encoder (lane-contiguous pixel map) -----------
  float acc2[4] = {b2[0], b2[0], b2[0], b2[0]};
  for (int grp = 0; grp < 4; ++grp) {
    #pragma unroll
    for (int p = 0; p < 4; ++p) {
      int pix = p * 256 + t;
      int y = pix >> 5, x = pix & 31;
      float win0[9], win1[9];
      #pragma unroll
      for (int ky = 0; ky < 3; ++ky) {
        #pragma unroll
        for (int kx = 0; kx < 3; ++kx) {
          int yy = y + ky - 1, xx = x + kx - 1;
          bool ok = (yy >= 0) && (yy <= 31) && (xx >= 0) && (xx <= 31);
          int q = ok ? yy * 32 + xx : 0;
          float v0 = m_p[q];
          float v1 = s_p[q] + g_p[q];
          win0[ky * 3 + kx] = ok ? v0 : 0.0f;
          win1[ky * 3 + kx] = ok ? v1 : 0.0f;
        }
      }
      #pragma unroll
      for (int ocl = 0; ocl < 8; ++ocl) {
        int oc = grp * 8 + ocl;
        const float* w = w1 + oc * 18;
        float acc = b1[oc];
        #pragma unroll
        for (int k = 0; k < 9; ++k) {
          acc += win0[k] * w[k];       // same per-pixel op order as round 1
          acc += win1[k] * w[9 + k];
        }
        hid[ocl][pix] = fmaxf(acc, 0.0f);
      }
    }
    __syncthreads();
    #pragma unroll
    for (int p = 0; p < 4; ++p) {
      int pix = p * 256 + t;
      int y = pix >> 5, x = pix & 31;
      float a = acc2[p];
      #pragma unroll
      for (int ocl = 0; ocl < 8; ++ocl) {
        int ic = grp * 8 + ocl;
        const float* w = w2 + ic * 9;
        #pragma unroll
        for (int ky = 0; ky < 3; ++ky) {
          #pragma unroll
          for (int kx = 0; kx < 3; ++kx) {
            int yy = y + ky - 1, xx = x + kx - 1;
            bool ok = (yy >= 0) && (yy <= 31) && (xx >= 0) && (xx <= 31);
            int q = ok ? yy * 32 + xx : 0;
            float hv = hid[ocl][q];
            a += (ok ? hv : 0.0f) * w[ky * 3 + kx];
          }
        }
      }
      acc2[p] = a;
    }
    __syncthreads();
  }
  #pragma unroll
  for (int p = 0; p < 4; ++p) {
    int pix = p * 256 + t;
    float c = 1.0f / (1.0f + expf(-acc2[p]));
    c_l[pix] = c;
    out_cost[b * HW + pix] = c;          // stride-1 across lanes: coalesced
  }
  __syncthreads();

  // ---------------- Phase 2: A* (wave 0, all-register + inc. tree) ---------
  if (t < 64) {
    const int lane = t;
    // goal via ballot (one-hot)
    int myg = -1;
    #pragma unroll
    for (int j = 0; j < 16; ++j) {
      int cell = j * 64 + lane;
      if (g_p[cell] > 0.5f) myg = cell;
    }
    unsigned long long gm = __ballot(myg >= 0);
    int src_lane = (int)__ffsll(gm) - 1;
    const int goal_idx = __shfl(myg, src_lane, 64);
    const int gy = goal_idx >> 5, gx = goal_idx & 31;

    unsigned int open_m = 0, hist_m = 0, obs_m = 0;
    float gr[16], hr[16], cr[16];
    unsigned int vr[16];
    unsigned int par_r[16];
    #pragma unroll
    for (int j = 0; j < 16; ++j) {
      int cell = j * 64 + lane;
      int y = cell >> 5, x = cell & 31;
      float cst = c_l[cell];
      cr[j] = cst;
      int dy = y - gy; dy = dy < 0 ? -dy : dy;
      int dx = x - gx; dx = dx < 0 ? -dx : dx;
      float e = sqrtf((float)(dy * dy + dx * dx));
      float heur = __fadd_rn((float)(dy + dx), __fmul_rn(0.001f, e));
      float hc = __fadd_rn(heur, cst);       // h4 = heuristic + cost
      hr[j] = hc;
      gr[j] = 0.0f;
      bool isobs = (m_p[cell] != 0.0f);
      bool isst  = (s_p[cell] > 0.5f);
      if (isobs) obs_m  |= 1u << j;
      if (isst)  open_m |= 1u << j;
      float f = 0.5f * (0.0f + hc);
      float ex = expf(__fmul_rn(-f, C_INV));
      vr[j] = isst ? __float_as_uint(ex) : 0u;
      par_r[j] = (unsigned)goal_idx;
    }

    // build the tournament tree (once)
    unsigned int pv[8], pj[8], qv[4], qj[4], ov[2], oj[2], rv, rj;
    #pragma unroll
    for (int a = 0; a < 8; ++a) PAIR_FIX(a);
    #pragma unroll
    for (int q = 0; q < 4; ++q) QUAD_FIX(q);
    #pragma unroll
    for (int o = 0; o < 2; ++o) OCT_FIX(o);
    ROOT_FIX();

    const int x = lane & 31, half = lane >> 5;
    const unsigned int lowbase = 1023u - (unsigned)lane;  // key = lowbase-64j

    for (int step = 0; step < 256; ++step) {
      // phase A: cross-lane value max (u32 compare == f32 compare, all >=0)
      unsigned int vmx = rv;
      DPPMAX32(vmx, 0x111);  // row_shr:1
      DPPMAX32(vmx, 0x112);  // row_shr:2
      DPPMAX32(vmx, 0x114);  // row_shr:4
      DPPMAX32(vmx, 0x118);  // row_shr:8
      DPPMAX32(vmx, 0x142);  // row_bcast:15
      DPPMAX32(vmx, 0x143);  // row_bcast:31
      const unsigned int svmax =
          (unsigned int)__builtin_amdgcn_readlane((int)vmx, 63);

      // phase B: winner cell. Fast path when exactly one lane holds the max.
      const unsigned long long tied = __ballot(rv == svmax);
      int sel_;
      if (__popcll(tied) == 1) {
        const int wl = (int)__ffsll(tied) - 1;                 // winner lane
        const unsigned int rjw =
            (unsigned int)__builtin_amdgcn_readlane((int)rj, wl);
        sel_ = (int)((rjw << 6) | (unsigned)wl);               // cell=j*64+ln
      } else {
        unsigned int lo = (rv == svmax) ? (lowbase - (rj << 6)) : 0u;
        DPPMAX32(lo, 0x111);
        DPPMAX32(lo, 0x112);
        DPPMAX32(lo, 0x114);
        DPPMAX32(lo, 0x118);
        DPPMAX32(lo, 0x142);
        DPPMAX32(lo, 0x143);
        const unsigned int klo =
            (unsigned int)__builtin_amdgcn_readlane((int)lo, 63);
        sel_ = 1023 - (int)klo;
      }
      const int sel = __builtin_amdgcn_readfirstlane(sel_);
      const int jsel = sel >> 6, owner = sel & 63;
      const int ys = sel >> 5, xs = sel & 31;
      const bool unsolved = (sel != goal_idx);

      // uniform register pair touched this step: {j0, j0+1}
      const int j0 = (ys > 0 ? ys - 1 : 0) >> 1;
      const int jP = (ys < 31 ? ys + 1 : 31) >> 1;     // B-candidate index
      const bool jS_is_j0 = (jsel == j0);
      const bool jP_is_j0 = (jP == j0);

      // per-lane geometry (candidates are always lane-owned cells)
      int dxs = x - xs; int adx = dxs < 0 ? -dxs : dxs;
      const bool act = (adx <= 1);
      const bool samep = (((ys ^ half) & 1) == 0);
      const int yA = samep ? ys : (ys - 1);
      const bool vAv = act && (samep ? (adx >= 1) : (yA >= 0));
      const int yB = ys + 1;
      const bool vBv = act && (!samep) && (yB <= 31);
      const int vjA = samep ? jsel : j0;               // A-candidate reg idx
      const bool vjA_is_j0 = (!samep) || jS_is_j0;

      bool obA = (obs_m  >> (vjA & 15)) & 1;
      bool opA = (open_m >> (vjA & 15)) & 1;
      bool hiA = (hist_m >> (vjA & 15)) & 1;
      bool obB = (obs_m  >> (jP & 15)) & 1;
      bool opB = (open_m >> (jP & 15)) & 1;
      bool hiB = (hist_m >> (jP & 15)) & 1;
      const bool canAn = vAv && obA && !opA && !hiA;   // new-open path
      const bool canAr = vAv && obA && opA;            // relax path (g>gsum)
      const bool canBn = vBv && obB && !opB && !hiB;
      const bool canBr = vBv && obB && opB;

      const bool ownerlane = (lane == owner);
      const bool closeU = unsolved && ownerlane;
      // change detection (pre-update bits)
      const bool histnew = ownerlane && !((hist_m >> (jsel & 15)) & 1);
      const bool opencl  = closeU && ((open_m >> (jsel & 15)) & 1);

      bool idxA = false, idxB = false;

      // merged uniform arm, binary-tree dispatch on SGPR j0 (depth 4)
      if (j0 < 8) {
        if (j0 < 4) {
          if (j0 < 2) { if (j0 == 0) ASTAR_ARM(0) else ASTAR_ARM(1) }
          else        { if (j0 == 2) ASTAR_ARM(2) else ASTAR_ARM(3) }
        } else {
          if (j0 < 6) { if (j0 == 4) ASTAR_ARM(4) else ASTAR_ARM(5) }
          else        { if (j0 == 6) ASTAR_ARM(6) else ASTAR_ARM(7) }
        }
      } else {
        if (j0 < 12) {
          if (j0 < 10) { if (j0 == 8)  ASTAR_ARM(8)  else ASTAR_ARM(9)  }
          else         { if (j0 == 10) ASTAR_ARM(10) else ASTAR_ARM(11) }
        } else {
          if (j0 < 14) { if (j0 == 12) ASTAR_ARM(12) else ASTAR_ARM(13) }
          else         { if (j0 == 14) ASTAR_ARM(14) else ASTAR_ARM(15) }
        }
      }

      // mask updates
      hist_m |= ownerlane ? (1u << (jsel & 15)) : 0u;
      unsigned int clr = closeU ? (1u << (jsel & 15)) : 0u;
      unsigned int aA  = idxA ? (1u << (vjA & 15)) : 0u;
      unsigned int aB  = idxB ? (1u << (jP & 15)) : 0u;
      open_m = (open_m & ~clr) | aA | aB;

      // freeze: nothing changed => fixed point => all remaining steps no-ops
      unsigned long long anych = __ballot(idxA || idxB || histnew || opencl);
      if (anych == 0ull) break;
    }

    hist_lds[lane] = hist_m;

    // ---------------- register backtrack ----------------
    // pack 16 x 10-bit parents into pp[6] (static unroll, constant shifts)
    unsigned int pp[6] = {0u, 0u, 0u, 0u, 0u, 0u};
    #pragma unroll
    for (int j = 0; j < 16; ++j) {
      const unsigned bp = (unsigned)j * 10u;
      const unsigned w = bp >> 5, s = bp & 31u;
      pp[w] |= par_r[j] << s;
      if (s > 22u) pp[w + 1] |= par_r[j] >> (32u - s);
    }

    // funnel-extract par[c] from the owner lane (uniform c -> scalar idx math)
    auto extract_par = [&](int c) -> int {
      const int jq = c >> 6, ownq = c & 63;
      const unsigned bp = (unsigned)jq * 10u;
      const unsigned w = bp >> 5, s = bp & 31u;
      unsigned lo = (w == 0u) ? pp[0] : (w == 1u) ? pp[1]
                  : (w == 2u) ? pp[2] : (w == 3u) ? pp[3] : pp[4];
      unsigned hi = (w == 0u) ? pp[1] : (w == 1u) ? pp[2]
                  : (w == 2u) ? pp[3] : (w == 3u) ? pp[4] : pp[5];
      unsigned long long both = ((unsigned long long)hi << 32) | lo;
      unsigned ext = (unsigned)(both >> s) & 1023u;
      return (int)__builtin_amdgcn_readlane((int)ext, ownq);
    };

    unsigned int path_m = 0u;
    if (lane == (goal_idx & 63)) path_m |= 1u << (goal_idx >> 6);
    int loc = extract_par(goal_idx);
    for (int i = 0; i < 255; ++i) {
      const int jc = loc >> 6, ow = loc & 63;
      const unsigned pm =
          (unsigned)__builtin_amdgcn_readlane((int)path_m, ow);
      if ((pm >> jc) & 1u) break;          // revisit => cycle => exact exit
      if (lane == ow) path_m |= 1u << jc;
      loc = extract_par(loc);
    }
    path_lds[lane] = path_m;
  }
  __syncthreads();

  // ---------------- Phase 3: outputs ----------------
  const int base = t * 4;
  float hv[4], pvv[4];
  #pragma unroll
  for (int p = 0; p < 4; ++p) {
    int cell = base + p;
    hv[p]  = (float)((hist_lds[cell & 63] >> (cell >> 6)) & 1);
    pvv[p] = (float)((path_lds[cell & 63] >> (cell >> 6)) & 1);
  }
  *reinterpret_cast<float4*>(out_hist + b * HW + base) =
      make_float4(hv[0], hv[1], hv[2], hv[3]);
  *reinterpret_cast<float4*>(out_path + b * HW + base) =
      make_float4(pvv[0], pvv[1], pvv[2], pvv[3]);
}

extern "C" void kernel_launch(void* const* d_in, const int* in_sizes, int n_in,
                              void* d_out, int out_size, void* d_ws, size_t ws_size,
                              hipStream_t stream) {
  (void)in_sizes; (void)n_in; (void)d_ws; (void)ws_size; (void)out_size;
  const float* maps  = (const float*)d_in[0];
  const float* start = (const float*)d_in[1];
  const float* goal  = (const float*)d_in[2];
  const float* w1    = (const float*)d_in[3];
  const float* b1    = (const float*)d_in[4];
  const float* w2    = (const float*)d_in[5];
  const float* b2    = (const float*)d_in[6];

  float* out      = (float*)d_out;
  float* out_hist = out;
  float* out_path = out + 64 * HW;
  float* out_cost = out + 128 * HW;

  fused_nastar<<<64, 256, 0, stream>>>(maps, start, goal, w1, b1, w2, b2,
                                       out_hist, out_path, out_cost);
}

// Round 6
// 147.770 us; speedup vs baseline: 1.0327x; 1.0327x over previous
//
#include <hip/hip_runtime.h>

// B=64, H=W=32, HW=1024, steps<=256, backtrack 255.
// Outputs: [histories 65536][paths 65536][pred_cost 65536] float32.
// Single fused kernel: 64 blocks (1 per batch) x 256 threads.
//   Phase 1 (all 256 thr): conv1(2->32)+ReLU, conv2(32->1)+sigmoid.
//            (unchanged, bit-identical accumulation order).
//   Phase 2 (wave 0 only): register-resident A*, EXACT round-4 loop.
//     Round-5 lesson (confirmed round-3): carrying extra state (par_r[16])
//     through the loop pushed VGPR 96->124 and the allocator SPILLED loop
//     state (WRITE_SIZE 768->864KB, dur 85->130us). The loop must keep the
//     96-VGPR allocation: par stays in LDS (write-only ds_write, never
//     waited on inside the loop).
//     BACKTRACK moved to registers POST-LOOP (live ranges don't overlap the
//     loop): all 64 lanes read par from LDS once (stride-64 shorts = 2-way
//     = free), pack 10-bit parents into pp[6], chase via scalar index math
//     + funnel shift + readlane (~60-90 cy/hop vs ~250 cy/hop for the old
//     lane-0 LDS pointer-chase with two dependent ~120cy LDS reads).
//     FREEZE BREAK: ballot==0 => fixed point => exact early exit.
//   Phase 3 (all): output writes (hist/path from per-lane bitmasks).

#define HW 1024

// DPP wave-64 u32 max step (compiler folds mov_dpp+max -> v_max_u32_dpp).
#define DPPMAX32(v, ctrl) do {                                                 \
    unsigned int _s = (unsigned int)__builtin_amdgcn_update_dpp(               \
        (int)(v), (int)(v), (ctrl), 0xf, 0xf, false);                          \
    (v) = (_s > (v)) ? _s : (v);                                               \
} while (0)

// Tournament-tree node repairs (value-only compare; tie keeps LEFT child =
// smaller index side; children cover contiguous index ranges => exact
// smallest-index tie-break).
#define PAIR_FIX(a_) { bool _r = vr[2*(a_)+1] > vr[2*(a_)];                    \
    pv[(a_)] = _r ? vr[2*(a_)+1] : vr[2*(a_)];                                 \
    pj[(a_)] = _r ? (unsigned)(2*(a_)+1) : (unsigned)(2*(a_)); }
#define QUAD_FIX(q_) { bool _r = pv[2*(q_)+1] > pv[2*(q_)];                    \
    qv[(q_)] = _r ? pv[2*(q_)+1] : pv[2*(q_)];                                 \
    qj[(q_)] = _r ? pj[2*(q_)+1] : pj[2*(q_)]; }
#define OCT_FIX(o_) { bool _r = qv[2*(o_)+1] > qv[2*(o_)];                     \
    ov[(o_)] = _r ? qv[2*(o_)+1] : qv[2*(o_)];                                 \
    oj[(o_)] = _r ? qj[2*(o_)+1] : qj[2*(o_)]; }
#define ROOT_FIX() { bool _r = ov[1] > ov[0];                                  \
    rv = _r ? ov[1] : ov[0]; rj = _r ? oj[1] : oj[0]; }

// One uniform arm of the A* update (J = j0, compile-time constant).
// EXACT round-4 body (two readlanes for gs/cs; par via LDS write outside).
#define ASTAR_ARM(J) {                                                         \
    constexpr int JN = ((J) < 15) ? (J) + 1 : 15;                              \
    const float gj0 = gr[(J)], hj0v = hr[(J)], cj0 = cr[(J)];                  \
    const float gj1 = gr[JN],  hj1v = hr[JN],  cj1 = cr[JN];                   \
    float gselv = jS_is_j0 ? gj0 : gj1;                                        \
    float cselv = jS_is_j0 ? cj0 : cj1;                                        \
    float gs = __uint_as_float((unsigned int)__builtin_amdgcn_readlane(        \
        (int)__float_as_uint(gselv), owner));                                  \
    float cs = __uint_as_float((unsigned int)__builtin_amdgcn_readlane(        \
        (int)__float_as_uint(cselv), owner));                                  \
    const float gsum = gs + cs;        /* g2 value (exact, as reference) */    \
    const float gA = vjA_is_j0 ? gj0 : gj1;                                    \
    const float hA = vjA_is_j0 ? hj0v : hj1v;                                  \
    const float gB = jP_is_j0 ? gj0 : gj1;                                     \
    const float hB = jP_is_j0 ? hj0v : hj1v;                                   \
    idxA = canAn || (canAr && (gA > gsum));                                    \
    idxB = canBn || (canBr && (gB > gsum));                                    \
    float fA = 0.5f * (gsum + hA);                                             \
    unsigned int nvA = __float_as_uint(expf(__fmul_rn(-fA, C_INV)));           \
    float fB = 0.5f * (gsum + hB);                                             \
    unsigned int nvB = __float_as_uint(expf(__fmul_rn(-fB, C_INV)));           \
    const bool uA0 = idxA && vjA_is_j0, uB0 = idxB && jP_is_j0;                \
    const bool uA1 = idxA && !vjA_is_j0, uB1 = idxB && !jP_is_j0;              \
    const bool u0 = uA0 || uB0, u1 = uA1 || uB1;                               \
    if (u0) { gr[(J)] = gsum; vr[(J)] = uA0 ? nvA : nvB; }                     \
    if (u1) { gr[JN]  = gsum; vr[JN]  = uA1 ? nvA : nvB; }                     \
    if (closeU &&  jS_is_j0) vr[(J)] = 0u;                                     \
    if (closeU && !jS_is_j0) vr[JN]  = 0u;                                     \
    constexpr int pa = (J) >> 1, pb = JN >> 1;                                 \
    PAIR_FIX(pa);                                                              \
    if constexpr (pb != pa) PAIR_FIX(pb);                                      \
    constexpr int qa = pa >> 1, qb = pb >> 1;                                  \
    QUAD_FIX(qa);                                                              \
    if constexpr (qb != qa) QUAD_FIX(qb);                                      \
    constexpr int oa = qa >> 1, ob = qb >> 1;                                  \
    OCT_FIX(oa);                                                               \
    if constexpr (ob != oa) OCT_FIX(ob);                                       \
    ROOT_FIX();                                                                \
  }

__global__ __launch_bounds__(256) void fused_nastar(
    const float* __restrict__ maps, const float* __restrict__ start,
    const float* __restrict__ goal, const float* __restrict__ w1,
    const float* __restrict__ b1, const float* __restrict__ w2,
    const float* __restrict__ b2, float* __restrict__ out_hist,
    float* __restrict__ out_path, float* __restrict__ out_cost) {
  __shared__ float hid[8][HW];            // 32 KB
  __shared__ float c_l[HW];               // 4 KB: cost (phase1 -> wave0 xfer)
  __shared__ unsigned short par[HW];      // 2 KB
  __shared__ unsigned int hist_lds[64];   // 256 B
  __shared__ unsigned int path_lds[64];   // 256 B

  const int t = threadIdx.x;
  const int b = blockIdx.x;
  const float C_INV = 0.17677669529663687f;  // float32(1/sqrt(32))

  const float* m_p = maps  + b * HW;
  const float* s_p = start + b * HW;
  const float* g_p = goal  + b * HW;

  // ---------------- Phase 1: encoder (lane-contiguous pixel map) -----------
  float acc2[4] = {b2[0], b2[0], b2[0], b2[0]};
  for (int grp = 0; grp < 4; ++grp) {
    #pragma unroll
    for (int p = 0; p < 4; ++p) {
      int pix = p * 256 + t;
      int y = pix >> 5, x = pix & 31;
      float win0[9], win1[9];
      #pragma unroll
      for (int ky = 0; ky < 3; ++ky) {
        #pragma unroll
        for (int kx = 0; kx < 3; ++kx) {
          int yy = y + ky - 1, xx = x + kx - 1;
          bool ok = (yy >= 0) && (yy <= 31) && (xx >= 0) && (xx <= 31);
          int q = ok ? yy * 32 + xx : 0;
          float v0 = m_p[q];
          float v1 = s_p[q] + g_p[q];
          win0[ky * 3 + kx] = ok ? v0 : 0.0f;
          win1[ky * 3 + kx] = ok ? v1 : 0.0f;
        }
      }
      #pragma unroll
      for (int ocl = 0; ocl < 8; ++ocl) {
        int oc = grp * 8 + ocl;
        const float* w = w1 + oc * 18;
        float acc = b1[oc];
        #pragma unroll
        for (int k = 0; k < 9; ++k) {
          acc += win0[k] * w[k];       // same per-pixel op order as round 1
          acc += win1[k] * w[9 + k];
        }
        hid[ocl][pix] = fmaxf(acc, 0.0f);
      }
    }
    __syncthreads();
    #pragma unroll
    for (int p = 0; p < 4; ++p) {
      int pix = p * 256 + t;
      int y = pix >> 5, x = pix & 31;
      float a = acc2[p];
      #pragma unroll
      for (int ocl = 0; ocl < 8; ++ocl) {
        int ic = grp * 8 + ocl;
        const float* w = w2 + ic * 9;
        #pragma unroll
        for (int ky = 0; ky < 3; ++ky) {
          #pragma unroll
          for (int kx = 0; kx < 3; ++kx) {
            int yy = y + ky - 1, xx = x + kx - 1;
            bool ok = (yy >= 0) && (yy <= 31) && (xx >= 0) && (xx <= 31);
            int q = ok ? yy * 32 + xx : 0;
            float hv = hid[ocl][q];
            a += (ok ? hv : 0.0f) * w[ky * 3 + kx];
          }
        }
      }
      acc2[p] = a;
    }
    __syncthreads();
  }
  #pragma unroll
  for (int p = 0; p < 4; ++p) {
    int pix = p * 256 + t;
    float c = 1.0f / (1.0f + expf(-acc2[p]));
    c_l[pix] = c;
    out_cost[b * HW + pix] = c;          // stride-1 across lanes: coalesced
  }
  __syncthreads();

  // ---------------- Phase 2: A* (wave 0, all-register + inc. tree) ---------
  if (t < 64) {
    const int lane = t;
    // goal via ballot (one-hot)
    int myg = -1;
    #pragma unroll
    for (int j = 0; j < 16; ++j) {
      int cell = j * 64 + lane;
      if (g_p[cell] > 0.5f) myg = cell;
    }
    unsigned long long gm = __ballot(myg >= 0);
    int src_lane = (int)__ffsll(gm) - 1;
    const int goal_idx = __shfl(myg, src_lane, 64);
    const int gy = goal_idx >> 5, gx = goal_idx & 31;

    unsigned int open_m = 0, hist_m = 0, obs_m = 0;
    float gr[16], hr[16], cr[16];
    unsigned int vr[16];
    #pragma unroll
    for (int j = 0; j < 16; ++j) {
      int cell = j * 64 + lane;
      int y = cell >> 5, x = cell & 31;
      float cst = c_l[cell];
      cr[j] = cst;
      int dy = y - gy; dy = dy < 0 ? -dy : dy;
      int dx = x - gx; dx = dx < 0 ? -dx : dx;
      float e = sqrtf((float)(dy * dy + dx * dx));
      float heur = __fadd_rn((float)(dy + dx), __fmul_rn(0.001f, e));
      float hc = __fadd_rn(heur, cst);       // h4 = heuristic + cost
      hr[j] = hc;
      gr[j] = 0.0f;
      bool isobs = (m_p[cell] != 0.0f);
      bool isst  = (s_p[cell] > 0.5f);
      if (isobs) obs_m  |= 1u << j;
      if (isst)  open_m |= 1u << j;
      float f = 0.5f * (0.0f + hc);
      float ex = expf(__fmul_rn(-f, C_INV));
      vr[j] = isst ? __float_as_uint(ex) : 0u;
      par[cell] = (unsigned short)goal_idx;
    }

    // build the tournament tree (once)
    unsigned int pv[8], pj[8], qv[4], qj[4], ov[2], oj[2], rv, rj;
    #pragma unroll
    for (int a = 0; a < 8; ++a) PAIR_FIX(a);
    #pragma unroll
    for (int q = 0; q < 4; ++q) QUAD_FIX(q);
    #pragma unroll
    for (int o = 0; o < 2; ++o) OCT_FIX(o);
    ROOT_FIX();

    const int x = lane & 31, half = lane >> 5;
    const unsigned int lowbase = 1023u - (unsigned)lane;  // key = lowbase-64j

    for (int step = 0; step < 256; ++step) {
      // phase A: cross-lane value max (u32 compare == f32 compare, all >=0)
      unsigned int vmx = rv;
      DPPMAX32(vmx, 0x111);  // row_shr:1
      DPPMAX32(vmx, 0x112);  // row_shr:2
      DPPMAX32(vmx, 0x114);  // row_shr:4
      DPPMAX32(vmx, 0x118);  // row_shr:8
      DPPMAX32(vmx, 0x142);  // row_bcast:15
      DPPMAX32(vmx, 0x143);  // row_bcast:31
      const unsigned int svmax =
          (unsigned int)__builtin_amdgcn_readlane((int)vmx, 63);

      // phase B: winner cell. Fast path when exactly one lane holds the max.
      const unsigned long long tied = __ballot(rv == svmax);
      int sel_;
      if (__popcll(tied) == 1) {
        const int wl = (int)__ffsll(tied) - 1;                 // winner lane
        const unsigned int rjw =
            (unsigned int)__builtin_amdgcn_readlane((int)rj, wl);
        sel_ = (int)((rjw << 6) | (unsigned)wl);               // cell=j*64+ln
      } else {
        unsigned int lo = (rv == svmax) ? (lowbase - (rj << 6)) : 0u;
        DPPMAX32(lo, 0x111);
        DPPMAX32(lo, 0x112);
        DPPMAX32(lo, 0x114);
        DPPMAX32(lo, 0x118);
        DPPMAX32(lo, 0x142);
        DPPMAX32(lo, 0x143);
        const unsigned int klo =
            (unsigned int)__builtin_amdgcn_readlane((int)lo, 63);
        sel_ = 1023 - (int)klo;
      }
      const int sel = __builtin_amdgcn_readfirstlane(sel_);
      const int jsel = sel >> 6, owner = sel & 63;
      const int ys = sel >> 5, xs = sel & 31;
      const bool unsolved = (sel != goal_idx);

      // uniform register pair touched this step: {j0, j0+1}
      const int j0 = (ys > 0 ? ys - 1 : 0) >> 1;
      const int jP = (ys < 31 ? ys + 1 : 31) >> 1;     // B-candidate index
      const bool jS_is_j0 = (jsel == j0);
      const bool jP_is_j0 = (jP == j0);

      // per-lane geometry (candidates are always lane-owned cells)
      int dxs = x - xs; int adx = dxs < 0 ? -dxs : dxs;
      const bool act = (adx <= 1);
      const bool samep = (((ys ^ half) & 1) == 0);
      const int yA = samep ? ys : (ys - 1);
      const bool vAv = act && (samep ? (adx >= 1) : (yA >= 0));
      const int yB = ys + 1;
      const bool vBv = act && (!samep) && (yB <= 31);
      const int cA = vAv ? (yA * 32 + x) : 0;
      const int cB = vBv ? (yB * 32 + x) : 0;
      const int vjA = samep ? jsel : j0;               // A-candidate reg idx
      const bool vjA_is_j0 = (!samep) || jS_is_j0;

      bool obA = (obs_m  >> (vjA & 15)) & 1;
      bool opA = (open_m >> (vjA & 15)) & 1;
      bool hiA = (hist_m >> (vjA & 15)) & 1;
      bool obB = (obs_m  >> (jP & 15)) & 1;
      bool opB = (open_m >> (jP & 15)) & 1;
      bool hiB = (hist_m >> (jP & 15)) & 1;
      const bool canAn = vAv && obA && !opA && !hiA;   // new-open path
      const bool canAr = vAv && obA && opA;            // relax path (g>gsum)
      const bool canBn = vBv && obB && !opB && !hiB;
      const bool canBr = vBv && obB && opB;

      const bool ownerlane = (lane == owner);
      const bool closeU = unsolved && ownerlane;
      // change detection (pre-update bits)
      const bool histnew = ownerlane && !((hist_m >> (jsel & 15)) & 1);
      const bool opencl  = closeU && ((open_m >> (jsel & 15)) & 1);

      bool idxA = false, idxB = false;

      // merged uniform arm, binary-tree dispatch on SGPR j0 (depth 4)
      if (j0 < 8) {
        if (j0 < 4) {
          if (j0 < 2) { if (j0 == 0) ASTAR_ARM(0) else ASTAR_ARM(1) }
          else        { if (j0 == 2) ASTAR_ARM(2) else ASTAR_ARM(3) }
        } else {
          if (j0 < 6) { if (j0 == 4) ASTAR_ARM(4) else ASTAR_ARM(5) }
          else        { if (j0 == 6) ASTAR_ARM(6) else ASTAR_ARM(7) }
        }
      } else {
        if (j0 < 12) {
          if (j0 < 10) { if (j0 == 8)  ASTAR_ARM(8)  else ASTAR_ARM(9)  }
          else         { if (j0 == 10) ASTAR_ARM(10) else ASTAR_ARM(11) }
        } else {
          if (j0 < 14) { if (j0 == 12) ASTAR_ARM(12) else ASTAR_ARM(13) }
          else         { if (j0 == 14) ASTAR_ARM(14) else ASTAR_ARM(15) }
        }
      }

      // par stays in LDS: write-only inside the loop, never waited on
      if (idxA) par[cA] = (unsigned short)sel;
      if (idxB) par[cB] = (unsigned short)sel;

      // mask updates
      hist_m |= ownerlane ? (1u << (jsel & 15)) : 0u;
      unsigned int clr = closeU ? (1u << (jsel & 15)) : 0u;
      unsigned int aA  = idxA ? (1u << (vjA & 15)) : 0u;
      unsigned int aB  = idxB ? (1u << (jP & 15)) : 0u;
      open_m = (open_m & ~clr) | aA | aB;

      // freeze: nothing changed => fixed point => all remaining steps no-ops
      unsigned long long anych = __ballot(idxA || idxB || histnew || opencl);
      if (anych == 0ull) break;
    }

    hist_lds[lane] = hist_m;

    // ---------------- register backtrack (post-loop; no loop pressure) -----
    // read this lane's 16 parents from LDS (stride-64 shorts = 2-way = free)
    // and pack 10-bit parents into pp[6] (static unroll, constant shifts)
    unsigned int pp[6] = {0u, 0u, 0u, 0u, 0u, 0u};
    #pragma unroll
    for (int j = 0; j < 16; ++j) {
      const unsigned prj = (unsigned)par[j * 64 + lane];
      const unsigned bp = (unsigned)j * 10u;
      const unsigned w = bp >> 5, s = bp & 31u;
      pp[w] |= prj << s;
      if (s > 22u) pp[w + 1] |= prj >> (32u - s);
    }

    // funnel-extract par[c] from the owner lane (uniform c -> scalar idx math)
    auto extract_par = [&](int c) -> int {
      const int jq = c >> 6, ownq = c & 63;
      const unsigned bp = (unsigned)jq * 10u;
      const unsigned w = bp >> 5, s = bp & 31u;
      unsigned lo = (w == 0u) ? pp[0] : (w == 1u) ? pp[1]
                  : (w == 2u) ? pp[2] : (w == 3u) ? pp[3] : pp[4];
      unsigned hi = (w == 0u) ? pp[1] : (w == 1u) ? pp[2]
                  : (w == 2u) ? pp[3] : (w == 3u) ? pp[4] : pp[5];
      unsigned long long both = ((unsigned long long)hi << 32) | lo;
      unsigned ext = (unsigned)(both >> s) & 1023u;
      return (int)__builtin_amdgcn_readlane((int)ext, ownq);
    };

    unsigned int path_m = 0u;
    if (lane == (goal_idx & 63)) path_m |= 1u << (goal_idx >> 6);
    int loc = extract_par(goal_idx);
    for (int i = 0; i < 255; ++i) {
      const int jc = loc >> 6, ow = loc & 63;
      const unsigned pm =
          (unsigned)__builtin_amdgcn_readlane((int)path_m, ow);
      if ((pm >> jc) & 1u) break;          // revisit => cycle => exact exit
      if (lane == ow) path_m |= 1u << jc;
      loc = extract_par(loc);
    }
    path_lds[lane] = path_m;
  }
  __syncthreads();

  // ---------------- Phase 3: outputs ----------------
  const int base = t * 4;
  float hv[4], pvv[4];
  #pragma unroll
  for (int p = 0; p < 4; ++p) {
    int cell = base + p;
    hv[p]  = (float)((hist_lds[cell & 63] >> (cell >> 6)) & 1);
    pvv[p] = (float)((path_lds[cell & 63] >> (cell >> 6)) & 1);
  }
  *reinterpret_cast<float4*>(out_hist + b * HW + base) =
      make_float4(hv[0], hv[1], hv[2], hv[3]);
  *reinterpret_cast<float4*>(out_path + b * HW + base) =
      make_float4(pvv[0], pvv[1], pvv[2], pvv[3]);
}

extern "C" void kernel_launch(void* const* d_in, const int* in_sizes, int n_in,
                              void* d_out, int out_size, void* d_ws, size_t ws_size,
                              hipStream_t stream) {
  (void)in_sizes; (void)n_in; (void)d_ws; (void)ws_size; (void)out_size;
  const float* maps  = (const float*)d_in[0];
  const float* start = (const float*)d_in[1];
  const float* goal  = (const float*)d_in[2];
  const float* w1    = (const float*)d_in[3];
  const float* b1    = (const float*)d_in[4];
  const float* w2    = (const float*)d_in[5];
  const float* b2    = (const float*)d_in[6];

  float* out      = (float*)d_out;
  float* out_hist = out;
  float* out_path = out + 64 * HW;
  float* out_cost = out + 128 * HW;

  fused_nastar<<<64, 256, 0, stream>>>(maps, start, goal, w1, b1, w2, b2,
                                       out_hist, out_path, out_cost);
}

// Round 7
// 142.939 us; speedup vs baseline: 1.0676x; 1.0338x over previous
//
#include <hip/hip_runtime.h>

// B=64, H=W=32, HW=1024, steps<=256, backtrack 255.
// Outputs: [histories 65536][paths 65536][pred_cost 65536] float32.
// Single fused kernel: 64 blocks (1 per batch) x 256 threads.
//   Phase 1 (all 256 thr): conv1(2->32)+ReLU, conv2(32->1)+sigmoid.
//            (unchanged, bit-identical accumulation order).
//   Phase 2 (wave 0 only): register-resident A*, round-4 structure.
//     Session ledger:
//       r3: switch jump-table + launch_bounds(,1) -> REGRESSED (indirect
//           dispatch + VGPR 124).
//       r5: par_r in loop -> VGPR 124 -> scratch spills (WRITE +96KB) -> 130us.
//       r6: register backtrack post-loop -> pp[6] STILL spilled to scratch
//           (WRITE 864KB, kernel capped at 96 VGPR) and cost ~3us vs r4's
//           lane-0 LDS chase. REVERTED here: backtrack hides under the
//           slowest block's A* anyway; only the critical block's chase counts.
//     This round's single isolated delta vs r4: SINGLE-READLANE gsum --
//     owner lane computes g[sel]+c[sel] locally (bit-identical f32 add),
//     one v_readlane broadcast instead of two (one fewer VALU->SALU hazard
//     window in the 256-deep serial chain).
//     FREEZE BREAK: ballot==0 => fixed point => exact early exit.
//   Phase 3 (all): backtrack (lane 0, LDS) + output writes.

#define HW 1024

// DPP wave-64 u32 max step (compiler folds mov_dpp+max -> v_max_u32_dpp).
#define DPPMAX32(v, ctrl) do {                                                 \
    unsigned int _s = (unsigned int)__builtin_amdgcn_update_dpp(               \
        (int)(v), (int)(v), (ctrl), 0xf, 0xf, false);                          \
    (v) = (_s > (v)) ? _s : (v);                                               \
} while (0)

// Tournament-tree node repairs (value-only compare; tie keeps LEFT child =
// smaller index side; children cover contiguous index ranges => exact
// smallest-index tie-break).
#define PAIR_FIX(a_) { bool _r = vr[2*(a_)+1] > vr[2*(a_)];                    \
    pv[(a_)] = _r ? vr[2*(a_)+1] : vr[2*(a_)];                                 \
    pj[(a_)] = _r ? (unsigned)(2*(a_)+1) : (unsigned)(2*(a_)); }
#define QUAD_FIX(q_) { bool _r = pv[2*(q_)+1] > pv[2*(q_)];                    \
    qv[(q_)] = _r ? pv[2*(q_)+1] : pv[2*(q_)];                                 \
    qj[(q_)] = _r ? pj[2*(q_)+1] : pj[2*(q_)]; }
#define OCT_FIX(o_) { bool _r = qv[2*(o_)+1] > qv[2*(o_)];                     \
    ov[(o_)] = _r ? qv[2*(o_)+1] : qv[2*(o_)];                                 \
    oj[(o_)] = _r ? qj[2*(o_)+1] : qj[2*(o_)]; }
#define ROOT_FIX() { bool _r = ov[1] > ov[0];                                  \
    rv = _r ? ov[1] : ov[0]; rj = _r ? oj[1] : oj[0]; }

// One uniform arm of the A* update (J = j0, compile-time constant).
#define ASTAR_ARM(J) {                                                         \
    constexpr int JN = ((J) < 15) ? (J) + 1 : 15;                              \
    const float gj0 = gr[(J)], hj0v = hr[(J)], cj0 = cr[(J)];                  \
    const float gj1 = gr[JN],  hj1v = hr[JN],  cj1 = cr[JN];                   \
    /* owner lane computes g[sel]+c[sel] locally; ONE broadcast */             \
    float gcs = (jS_is_j0 ? gj0 : gj1) + (jS_is_j0 ? cj0 : cj1);               \
    const float gsum = __uint_as_float(                                        \
        (unsigned int)__builtin_amdgcn_readlane(                               \
            (int)__float_as_uint(gcs), owner));                                \
    const float gA = vjA_is_j0 ? gj0 : gj1;                                    \
    const float hA = vjA_is_j0 ? hj0v : hj1v;                                  \
    const float gB = jP_is_j0 ? gj0 : gj1;                                     \
    const float hB = jP_is_j0 ? hj0v : hj1v;                                   \
    idxA = canAn || (canAr && (gA > gsum));                                    \
    idxB = canBn || (canBr && (gB > gsum));                                    \
    float fA = 0.5f * (gsum + hA);                                             \
    unsigned int nvA = __float_as_uint(expf(__fmul_rn(-fA, C_INV)));           \
    float fB = 0.5f * (gsum + hB);                                             \
    unsigned int nvB = __float_as_uint(expf(__fmul_rn(-fB, C_INV)));           \
    const bool uA0 = idxA && vjA_is_j0, uB0 = idxB && jP_is_j0;                \
    const bool uA1 = idxA && !vjA_is_j0, uB1 = idxB && !jP_is_j0;              \
    const bool u0 = uA0 || uB0, u1 = uA1 || uB1;                               \
    if (u0) { gr[(J)] = gsum; vr[(J)] = uA0 ? nvA : nvB; }                     \
    if (u1) { gr[JN]  = gsum; vr[JN]  = uA1 ? nvA : nvB; }                     \
    if (closeU &&  jS_is_j0) vr[(J)] = 0u;                                     \
    if (closeU && !jS_is_j0) vr[JN]  = 0u;                                     \
    constexpr int pa = (J) >> 1, pb = JN >> 1;                                 \
    PAIR_FIX(pa);                                                              \
    if constexpr (pb != pa) PAIR_FIX(pb);                                      \
    constexpr int qa = pa >> 1, qb = pb >> 1;                                  \
    QUAD_FIX(qa);                                                              \
    if constexpr (qb != qa) QUAD_FIX(qb);                                      \
    constexpr int oa = qa >> 1, ob = qb >> 1;                                  \
    OCT_FIX(oa);                                                               \
    if constexpr (ob != oa) OCT_FIX(ob);                                       \
    ROOT_FIX();                                                                \
  }

__global__ __launch_bounds__(256) void fused_nastar(
    const float* __restrict__ maps, const float* __restrict__ start,
    const float* __restrict__ goal, const float* __restrict__ w1,
    const float* __restrict__ b1, const float* __restrict__ w2,
    const float* __restrict__ b2, float* __restrict__ out_hist,
    float* __restrict__ out_path, float* __restrict__ out_cost) {
  __shared__ float hid[8][HW];            // 32 KB
  __shared__ float c_l[HW];               // 4 KB: cost (phase1 -> wave0 xfer)
  __shared__ unsigned short par[HW];      // 2 KB
  __shared__ unsigned char path_sh[HW];   // 1 KB
  __shared__ unsigned int hist_lds[64];   // 256 B

  const int t = threadIdx.x;
  const int b = blockIdx.x;
  const float C_INV = 0.17677669529663687f;  // float32(1/sqrt(32))

  const float* m_p = maps  + b * HW;
  const float* s_p = start + b * HW;
  const float* g_p = goal  + b * HW;

  // ---------------- Phase 1: encoder (lane-contiguous pixel map) -----------
  float acc2[4] = {b2[0], b2[0], b2[0], b2[0]};
  for (int grp = 0; grp < 4; ++grp) {
    #pragma unroll
    for (int p = 0; p < 4; ++p) {
      int pix = p * 256 + t;
      int y = pix >> 5, x = pix & 31;
      float win0[9], win1[9];
      #pragma unroll
      for (int ky = 0; ky < 3; ++ky) {
        #pragma unroll
        for (int kx = 0; kx < 3; ++kx) {
          int yy = y + ky - 1, xx = x + kx - 1;
          bool ok = (yy >= 0) && (yy <= 31) && (xx >= 0) && (xx <= 31);
          int q = ok ? yy * 32 + xx : 0;
          float v0 = m_p[q];
          float v1 = s_p[q] + g_p[q];
          win0[ky * 3 + kx] = ok ? v0 : 0.0f;
          win1[ky * 3 + kx] = ok ? v1 : 0.0f;
        }
      }
      #pragma unroll
      for (int ocl = 0; ocl < 8; ++ocl) {
        int oc = grp * 8 + ocl;
        const float* w = w1 + oc * 18;
        float acc = b1[oc];
        #pragma unroll
        for (int k = 0; k < 9; ++k) {
          acc += win0[k] * w[k];       // same per-pixel op order as round 1
          acc += win1[k] * w[9 + k];
        }
        hid[ocl][pix] = fmaxf(acc, 0.0f);
      }
    }
    __syncthreads();
    #pragma unroll
    for (int p = 0; p < 4; ++p) {
      int pix = p * 256 + t;
      int y = pix >> 5, x = pix & 31;
      float a = acc2[p];
      #pragma unroll
      for (int ocl = 0; ocl < 8; ++ocl) {
        int ic = grp * 8 + ocl;
        const float* w = w2 + ic * 9;
        #pragma unroll
        for (int ky = 0; ky < 3; ++ky) {
          #pragma unroll
          for (int kx = 0; kx < 3; ++kx) {
            int yy = y + ky - 1, xx = x + kx - 1;
            bool ok = (yy >= 0) && (yy <= 31) && (xx >= 0) && (xx <= 31);
            int q = ok ? yy * 32 + xx : 0;
            float hv = hid[ocl][q];
            a += (ok ? hv : 0.0f) * w[ky * 3 + kx];
          }
        }
      }
      acc2[p] = a;
    }
    __syncthreads();
  }
  #pragma unroll
  for (int p = 0; p < 4; ++p) {
    int pix = p * 256 + t;
    float c = 1.0f / (1.0f + expf(-acc2[p]));
    c_l[pix] = c;
    out_cost[b * HW + pix] = c;          // stride-1 across lanes: coalesced
  }
  __syncthreads();

  // ---------------- Phase 2: A* (wave 0, all-register + inc. tree) ---------
  if (t < 64) {
    const int lane = t;
    reinterpret_cast<int4*>(path_sh)[lane] = make_int4(0, 0, 0, 0);
    // goal via ballot (one-hot)
    int myg = -1;
    #pragma unroll
    for (int j = 0; j < 16; ++j) {
      int cell = j * 64 + lane;
      if (g_p[cell] > 0.5f) myg = cell;
    }
    unsigned long long gm = __ballot(myg >= 0);
    int src_lane = (int)__ffsll(gm) - 1;
    const int goal_idx = __shfl(myg, src_lane, 64);
    const int gy = goal_idx >> 5, gx = goal_idx & 31;

    unsigned int open_m = 0, hist_m = 0, obs_m = 0;
    float gr[16], hr[16], cr[16];
    unsigned int vr[16];
    #pragma unroll
    for (int j = 0; j < 16; ++j) {
      int cell = j * 64 + lane;
      int y = cell >> 5, x = cell & 31;
      float cst = c_l[cell];
      cr[j] = cst;
      int dy = y - gy; dy = dy < 0 ? -dy : dy;
      int dx = x - gx; dx = dx < 0 ? -dx : dx;
      float e = sqrtf((float)(dy * dy + dx * dx));
      float heur = __fadd_rn((float)(dy + dx), __fmul_rn(0.001f, e));
      float hc = __fadd_rn(heur, cst);       // h4 = heuristic + cost
      hr[j] = hc;
      gr[j] = 0.0f;
      bool isobs = (m_p[cell] != 0.0f);
      bool isst  = (s_p[cell] > 0.5f);
      if (isobs) obs_m  |= 1u << j;
      if (isst)  open_m |= 1u << j;
      float f = 0.5f * (0.0f + hc);
      float ex = expf(__fmul_rn(-f, C_INV));
      vr[j] = isst ? __float_as_uint(ex) : 0u;
      par[cell] = (unsigned short)goal_idx;
    }

    // build the tournament tree (once)
    unsigned int pv[8], pj[8], qv[4], qj[4], ov[2], oj[2], rv, rj;
    #pragma unroll
    for (int a = 0; a < 8; ++a) PAIR_FIX(a);
    #pragma unroll
    for (int q = 0; q < 4; ++q) QUAD_FIX(q);
    #pragma unroll
    for (int o = 0; o < 2; ++o) OCT_FIX(o);
    ROOT_FIX();

    const int x = lane & 31, half = lane >> 5;
    const unsigned int lowbase = 1023u - (unsigned)lane;  // key = lowbase-64j

    for (int step = 0; step < 256; ++step) {
      // phase A: cross-lane value max (u32 compare == f32 compare, all >=0)
      unsigned int vmx = rv;
      DPPMAX32(vmx, 0x111);  // row_shr:1
      DPPMAX32(vmx, 0x112);  // row_shr:2
      DPPMAX32(vmx, 0x114);  // row_shr:4
      DPPMAX32(vmx, 0x118);  // row_shr:8
      DPPMAX32(vmx, 0x142);  // row_bcast:15
      DPPMAX32(vmx, 0x143);  // row_bcast:31
      const unsigned int svmax =
          (unsigned int)__builtin_amdgcn_readlane((int)vmx, 63);

      // phase B: winner cell. Fast path when exactly one lane holds the max.
      const unsigned long long tied = __ballot(rv == svmax);
      int sel_;
      if (__popcll(tied) == 1) {
        const int wl = (int)__ffsll(tied) - 1;                 // winner lane
        const unsigned int rjw =
            (unsigned int)__builtin_amdgcn_readlane((int)rj, wl);
        sel_ = (int)((rjw << 6) | (unsigned)wl);               // cell=j*64+ln
      } else {
        unsigned int lo = (rv == svmax) ? (lowbase - (rj << 6)) : 0u;
        DPPMAX32(lo, 0x111);
        DPPMAX32(lo, 0x112);
        DPPMAX32(lo, 0x114);
        DPPMAX32(lo, 0x118);
        DPPMAX32(lo, 0x142);
        DPPMAX32(lo, 0x143);
        const unsigned int klo =
            (unsigned int)__builtin_amdgcn_readlane((int)lo, 63);
        sel_ = 1023 - (int)klo;
      }
      const int sel = __builtin_amdgcn_readfirstlane(sel_);
      const int jsel = sel >> 6, owner = sel & 63;
      const int ys = sel >> 5, xs = sel & 31;
      const bool unsolved = (sel != goal_idx);

      // uniform register pair touched this step: {j0, j0+1}
      const int j0 = (ys > 0 ? ys - 1 : 0) >> 1;
      const int jP = (ys < 31 ? ys + 1 : 31) >> 1;     // B-candidate index
      const bool jS_is_j0 = (jsel == j0);
      const bool jP_is_j0 = (jP == j0);

      // per-lane geometry (candidates are always lane-owned cells)
      int dxs = x - xs; int adx = dxs < 0 ? -dxs : dxs;
      const bool act = (adx <= 1);
      const bool samep = (((ys ^ half) & 1) == 0);
      const int yA = samep ? ys : (ys - 1);
      const bool vAv = act && (samep ? (adx >= 1) : (yA >= 0));
      const int yB = ys + 1;
      const bool vBv = act && (!samep) && (yB <= 31);
      const int cA = vAv ? (yA * 32 + x) : 0;
      const int cB = vBv ? (yB * 32 + x) : 0;
      const int vjA = samep ? jsel : j0;               // A-candidate reg idx
      const bool vjA_is_j0 = (!samep) || jS_is_j0;

      bool obA = (obs_m  >> (vjA & 15)) & 1;
      bool opA = (open_m >> (vjA & 15)) & 1;
      bool hiA = (hist_m >> (vjA & 15)) & 1;
      bool obB = (obs_m  >> (jP & 15)) & 1;
      bool opB = (open_m >> (jP & 15)) & 1;
      bool hiB = (hist_m >> (jP & 15)) & 1;
      const bool canAn = vAv && obA && !opA && !hiA;   // new-open path
      const bool canAr = vAv && obA && opA;            // relax path (g>gsum)
      const bool canBn = vBv && obB && !opB && !hiB;
      const bool canBr = vBv && obB && opB;

      const bool ownerlane = (lane == owner);
      const bool closeU = unsolved && ownerlane;
      // change detection (pre-update bits)
      const bool histnew = ownerlane && !((hist_m >> (jsel & 15)) & 1);
      const bool opencl  = closeU && ((open_m >> (jsel & 15)) & 1);

      bool idxA = false, idxB = false;

      // merged uniform arm, binary-tree dispatch on SGPR j0 (depth 4)
      if (j0 < 8) {
        if (j0 < 4) {
          if (j0 < 2) { if (j0 == 0) ASTAR_ARM(0) else ASTAR_ARM(1) }
          else        { if (j0 == 2) ASTAR_ARM(2) else ASTAR_ARM(3) }
        } else {
          if (j0 < 6) { if (j0 == 4) ASTAR_ARM(4) else ASTAR_ARM(5) }
          else        { if (j0 == 6) ASTAR_ARM(6) else ASTAR_ARM(7) }
        }
      } else {
        if (j0 < 12) {
          if (j0 < 10) { if (j0 == 8)  ASTAR_ARM(8)  else ASTAR_ARM(9)  }
          else         { if (j0 == 10) ASTAR_ARM(10) else ASTAR_ARM(11) }
        } else {
          if (j0 < 14) { if (j0 == 12) ASTAR_ARM(12) else ASTAR_ARM(13) }
          else         { if (j0 == 14) ASTAR_ARM(14) else ASTAR_ARM(15) }
        }
      }

      // par stays in LDS: write-only inside the loop, never waited on
      if (idxA) par[cA] = (unsigned short)sel;
      if (idxB) par[cB] = (unsigned short)sel;

      // mask updates
      hist_m |= ownerlane ? (1u << (jsel & 15)) : 0u;
      unsigned int clr = closeU ? (1u << (jsel & 15)) : 0u;
      unsigned int aA  = idxA ? (1u << (vjA & 15)) : 0u;
      unsigned int aB  = idxB ? (1u << (jP & 15)) : 0u;
      open_m = (open_m & ~clr) | aA | aB;

      // freeze: nothing changed => fixed point => all remaining steps no-ops
      unsigned long long anych = __ballot(idxA || idxB || histnew || opencl);
      if (anych == 0ull) break;
    }

    hist_lds[lane] = hist_m;

    // backtrack (parent table static; revisit => cycle => exact early exit)
    if (lane == 0) {
      path_sh[goal_idx] = 1;
      int loc = par[goal_idx];
      for (int i = 0; i < 255; ++i) {
        if (path_sh[loc]) break;
        path_sh[loc] = 1;
        loc = par[loc];
      }
    }
  }
  __syncthreads();

  // ---------------- Phase 3: outputs ----------------
  const int base = t * 4;
  float hv[4], pvv[4];
  #pragma unroll
  for (int p = 0; p < 4; ++p) {
    int cell = base + p;
    hv[p]  = (float)((hist_lds[cell & 63] >> (cell >> 6)) & 1);
    pvv[p] = (float)path_sh[cell];
  }
  *reinterpret_cast<float4*>(out_hist + b * HW + base) =
      make_float4(hv[0], hv[1], hv[2], hv[3]);
  *reinterpret_cast<float4*>(out_path + b * HW + base) =
      make_float4(pvv[0], pvv[1], pvv[2], pvv[3]);
}

extern "C" void kernel_launch(void* const* d_in, const int* in_sizes, int n_in,
                              void* d_out, int out_size, void* d_ws, size_t ws_size,
                              hipStream_t stream) {
  (void)in_sizes; (void)n_in; (void)d_ws; (void)ws_size; (void)out_size;
  const float* maps  = (const float*)d_in[0];
  const float* start = (const float*)d_in[1];
  const float* goal  = (const float*)d_in[2];
  const float* w1    = (const float*)d_in[3];
  const float* b1    = (const float*)d_in[4];
  const float* w2    = (const float*)d_in[5];
  const float* b2    = (const float*)d_in[6];

  float* out      = (float*)d_out;
  float* out_hist = out;
  float* out_path = out + 64 * HW;
  float* out_cost = out + 128 * HW;

  fused_nastar<<<64, 256, 0, stream>>>(maps, start, goal, w1, b1, w2, b2,
                                       out_hist, out_path, out_cost);
}